// Round 4
// baseline (23566.347 us; speedup 1.0000x reference)
//
#include <hip/hip_runtime.h>
#include <hip/hip_fp16.h>

// LSTM B=8192 S=1024 H=256 — round 4: dual-set staggered recurrence.
// 256 blocks x 512 thr, 1 block/CU (launch_bounds(512,2) -> 256-VGPR class;
// round 3 proved (512,4) spills wfrag). Pairs {B, B^8} (same XCD, verified
// r2/r3) share 64 batch rows = 2 independent sets of 32 (A, B). Each block
// owns j-half (512 gate rows interleaved n'=j*4+g, 128 KB fp16 = 128 regs,
// shared by BOTH sets). Per t: phase A (step t of set A) then phase B —
// set X's exchange round-trip is hidden behind set Y's compute, so the
// peer-flag spin is pre-satisfied. 8 KB publish/phase, 3 barriers/phase.
// c-state fp32 in VGPRs; f,i,cs,o of one (b,j) in one acc f32x4.

typedef _Float16 f16x8 __attribute__((ext_vector_type(8)));
typedef float f32x4 __attribute__((ext_vector_type(4)));
typedef unsigned int u32;
typedef unsigned short u16;

#define WINT_OFF 0u
#define W0B_OFF  524288u
#define FLAG_OFF 528384u   // int[256 blocks][2 sets][16] = 32 KB
#define PUB_OFF  1048576u  // u16 quarters: (((s*2+pr)*128 + pid)*2 + mi)*4096 (8 MB)

static __device__ __forceinline__ float fast_exp2(float x) {
#if __has_builtin(__builtin_amdgcn_exp2f)
  return __builtin_amdgcn_exp2f(x);
#else
  return exp2f(x);
#endif
}
static __device__ __forceinline__ float fast_rcp(float x) {
#if __has_builtin(__builtin_amdgcn_rcpf)
  return __builtin_amdgcn_rcpf(x);
#else
  return 1.0f / x;
#endif
}
static __device__ __forceinline__ float fsig(float x) {
  return fast_rcp(1.0f + fast_exp2(-1.44269504f * x));
}
static __device__ __forceinline__ float ftanh_(float x) {
  float e = fast_exp2(2.88539008f * x);
  return 1.0f - 2.0f * fast_rcp(e + 1.0f);
}
static __device__ __forceinline__ u16 f16b(float f) {
  union { _Float16 h; u16 u; } cv; cv.h = (_Float16)f; return cv.u;
}
static __device__ __forceinline__ float h2f(u16 u) {
  union { u16 u; _Float16 h; } cv; cv.u = u; return (float)cv.h;
}

// Wint[n'][k], n' = j*4+g (gates of one j adjacent); w0b = packed fp16 {w0, bias}.
__global__ void lstm_prep(const float* __restrict__ Wf, const float* __restrict__ Wi,
                          const float* __restrict__ Wc, const float* __restrict__ Wo,
                          const float* __restrict__ bf_, const float* __restrict__ bi_,
                          const float* __restrict__ bc_, const float* __restrict__ bo_,
                          u16* __restrict__ Wint, u32* __restrict__ w0b) {
  int np = blockIdx.x;      // 0..1023
  int k  = threadIdx.x;     // 0..255
  int g = np & 3, j = np >> 2;
  const float* Ws = (g == 0) ? Wf : (g == 1) ? Wi : (g == 2) ? Wc : Wo;
  Wint[np * 256 + k] = f16b(Ws[j * 257 + 1 + k]);
  if (k == 0) {
    const float* bs = (g == 0) ? bf_ : (g == 1) ? bi_ : (g == 2) ? bc_ : bo_;
    w0b[np] = (u32)f16b(Ws[j * 257]) | ((u32)f16b(bs[j]) << 16);
  }
}

// Zero parity-0 publish quarters of both sets (h_0 = 0), flags, out = bout.
__global__ void lstm_zero(uint4* __restrict__ pub4, uint4* __restrict__ flags4,
                          float* __restrict__ out, const float* __restrict__ bout) {
  int idx = blockIdx.x * 256 + threadIdx.x;
  uint4 z = uint4{0, 0, 0, 0};
  if (idx < 131072) pub4[idx] = z;                        // set0 parity0 (2 MB)
  else if (idx < 262144) pub4[idx - 131072 + 262144] = z; // set1 parity0 (2 MB)
  else if (idx < 264192) flags4[idx - 262144] = z;        // flags (32 KB)
  else { int o = idx - 264192; if (o < 8192) out[o] = bout[0]; }
}

__global__ __launch_bounds__(512, 2) void lstm_main(
    const u16* __restrict__ Wint, const u32* __restrict__ w0b,
    const float* __restrict__ x, const float* __restrict__ Wout,
    float* __restrict__ out, u16* __restrict__ pub, int* __restrict__ flags) {

  __shared__ __align__(16) u16 stg[2][2][32 * 128];  // [set][0=own half,1=peer half]
  __shared__ u32 lw0b[512];

  const int tid  = threadIdx.x;
  const int wv   = tid >> 6;
  const int lane = tid & 63;
  const int l15  = lane & 15;
  const int quad = lane >> 4;
  const int B    = blockIdx.x;
  const int mi   = (B >> 3) & 1;
  const int peer = B ^ 8;
  const int pid  = (B & 7) | ((B >> 4) << 3);   // pair 0..127
  const int rows0 = pid * 64;                   // set0: +[0,32), set1: +[32,64)

  // ---- one-time: W A-fragments (128 regs, shared by both sets) ----
  f16x8 wfrag[4][8];
#pragma unroll
  for (int mm = 0; mm < 4; ++mm)
#pragma unroll
    for (int kt = 0; kt < 8; ++kt)
      wfrag[mm][kt] = *(const f16x8*)(Wint +
          (size_t)(mi * 512 + (wv * 4 + mm) * 16 + l15) * 256 + kt * 32 + quad * 8);
  lw0b[tid] = w0b[mi * 512 + tid];
  ((uint4*)&stg[0][0][0])[tid] = uint4{0, 0, 0, 0};   // h_0 own halves = 0
  ((uint4*)&stg[1][0][0])[tid] = uint4{0, 0, 0, 0};

  float cst[2][4][2];
#pragma unroll
  for (int s = 0; s < 2; ++s)
#pragma unroll
    for (int mm = 0; mm < 4; ++mm)
#pragma unroll
      for (int bt = 0; bt < 2; ++bt) cst[s][mm][bt] = 0.0f;

  const float* xp[2] = { x + (size_t)(rows0 + l15) * 1024,
                         x + (size_t)(rows0 + 32 + l15) * 1024 };
  int* const myflag[2] = { flags + B * 32,    flags + B * 32 + 16 };
  int* const pflag[2]  = { flags + peer * 32, flags + peer * 32 + 16 };

  __syncthreads();

#pragma unroll 1
  for (int t = 0; t < 1024; ++t) {
    const int pr = t & 1;
#pragma unroll
    for (int s = 0; s < 2; ++s) {
      // 1. peer's h_t for this set (pre-satisfied: published one phase ago)
      while (__hip_atomic_load(pflag[s], __ATOMIC_RELAXED, __HIP_MEMORY_SCOPE_AGENT) < t)
        __builtin_amdgcn_s_sleep(1);

      // 2. DMA peer half -> stg[s][1] (in flight under acc-init + own-K)
      const u16* ppub = pub + (size_t)((((s * 2 + pr) * 128 + pid) * 2 + (1 - mi)) * 4096);
      __builtin_amdgcn_global_load_lds(
          (const __attribute__((address_space(1))) u32*)(ppub + tid * 8),
          (__attribute__((address_space(3))) u32*)(&stg[s][1][wv * 512]), 16, 0, 0);

      // 3. acc init = x*w0 + bias
      float xv0 = xp[s][t], xv1 = xp[s][16 * 1024 + t];
      f32x4 acc[4][2];
#pragma unroll
      for (int mm = 0; mm < 4; ++mm) {
        uint4 pk = *(const uint4*)&lw0b[(wv * 4 + mm) * 16 + quad * 4];
        u32 pka[4] = {pk.x, pk.y, pk.z, pk.w};
#pragma unroll
        for (int r = 0; r < 4; ++r) {
          float w0f = h2f((u16)pka[r]), bsf = h2f((u16)(pka[r] >> 16));
          acc[mm][0][r] = xv0 * w0f + bsf;
          acc[mm][1][r] = xv1 * w0f + bsf;
        }
      }

      // 4. own-half K (reads stg[s][0]; overlaps DMA)
#pragma unroll
      for (int ktl = 0; ktl < 4; ++ktl) {
        f16x8 bb[2];
#pragma unroll
        for (int bt = 0; bt < 2; ++bt) {
          int b = bt * 16 + l15;
          int c = (ktl * 4 + quad) ^ (b & 7);
          bb[bt] = *(const f16x8*)&stg[s][0][b * 128 + c * 8];
        }
#pragma unroll
        for (int mm = 0; mm < 4; ++mm)
#pragma unroll
          for (int bt = 0; bt < 2; ++bt)
            acc[mm][bt] = __builtin_amdgcn_mfma_f32_16x16x32_f16(
                wfrag[mm][mi * 4 + ktl], bb[bt], acc[mm][bt], 0, 0, 0);
      }
      __syncthreads();   // DMA drained; all waves done with stg[s][0] h_t

      // 5. peer-half K (reads stg[s][1])
#pragma unroll
      for (int ktl = 0; ktl < 4; ++ktl) {
        f16x8 bb[2];
#pragma unroll
        for (int bt = 0; bt < 2; ++bt) {
          int b = bt * 16 + l15;
          int c = (ktl * 4 + quad) ^ (b & 7);
          bb[bt] = *(const f16x8*)&stg[s][1][b * 128 + c * 8];
        }
#pragma unroll
        for (int mm = 0; mm < 4; ++mm)
#pragma unroll
          for (int bt = 0; bt < 2; ++bt)
            acc[mm][bt] = __builtin_amdgcn_mfma_f32_16x16x32_f16(
                wfrag[mm][(1 - mi) * 4 + ktl], bb[bt], acc[mm][bt], 0, 0, 0);
      }

      // 6. elementwise: f,i,cs,o in one f32x4; h_{t+1} -> stg[s][0] (swizzled)
#pragma unroll
      for (int mm = 0; mm < 4; ++mm) {
        int jl = (wv * 4 + mm) * 4 + quad;   // local j 0..127
#pragma unroll
        for (int bt = 0; bt < 2; ++bt) {
          int b = bt * 16 + l15;
          float fg = acc[mm][bt][0], ig = acc[mm][bt][1];
          float cg = acc[mm][bt][2], og = acc[mm][bt][3];
          float c_ = fsig(fg) * cst[s][mm][bt] + fsig(ig) * ftanh_(cg);
          cst[s][mm][bt] = c_;
          float hv = fsig(og) * ftanh_(c_);
          stg[s][0][b * 128 + ((jl >> 3) ^ (b & 7)) * 8 + (jl & 7)] = f16b(hv);
        }
      }
      __syncthreads();   // stg[s][0] h_{t+1} complete; stg[s][1] reads done

      // 7. publish own half (one coalesced uint4/thread = 8 KB)
      uint4 v = ((const uint4*)&stg[s][0][0])[tid];
      u16* mypub = pub + (size_t)((((s * 2 + (pr ^ 1)) * 128 + pid) * 2 + mi) * 4096);
      *(uint4*)(mypub + tid * 8) = v;
      __syncthreads();   // all threads' stores drained (vmcnt 0) before flag
      if (tid == 0)
        __hip_atomic_store(myflag[s], t + 1, __ATOMIC_RELAXED, __HIP_MEMORY_SCOPE_AGENT);
    }
  }

  // ---- out[b] += (own-half h_1024) . Wout  (out pre-set to bout) ----
#pragma unroll
  for (int s = 0; s < 2; ++s) {
    int row = tid >> 4, seg = tid & 15;
    f16x8 hv = *(const f16x8*)&stg[s][0][row * 128 + (seg ^ (row & 7)) * 8];
    float a = 0.0f;
#pragma unroll
    for (int e = 0; e < 8; ++e) a += (float)hv[e] * Wout[mi * 128 + seg * 8 + e];
#pragma unroll
    for (int mask = 1; mask < 16; mask <<= 1) a += __shfl_xor(a, mask, 16);
    if (seg == 0) atomicAdd(&out[rows0 + s * 32 + row], a);
  }
}

extern "C" void kernel_launch(void* const* d_in, const int* in_sizes, int n_in,
                              void* d_out, int out_size, void* d_ws, size_t ws_size,
                              hipStream_t stream) {
  const float* x    = (const float*)d_in[0];
  const float* Wf   = (const float*)d_in[1];
  const float* bf_  = (const float*)d_in[2];
  const float* Wi   = (const float*)d_in[3];
  const float* bi_  = (const float*)d_in[4];
  const float* Wc   = (const float*)d_in[5];
  const float* bc_  = (const float*)d_in[6];
  const float* Wo   = (const float*)d_in[7];
  const float* bo_  = (const float*)d_in[8];
  const float* Wout = (const float*)d_in[9];
  const float* bout = (const float*)d_in[10];

  u16* Wint  = (u16*)((char*)d_ws + WINT_OFF);
  u32* w0b   = (u32*)((char*)d_ws + W0B_OFF);
  int* flags = (int*)((char*)d_ws + FLAG_OFF);
  u16* pub   = (u16*)((char*)d_ws + PUB_OFF);

  lstm_prep<<<1024, 256, 0, stream>>>(Wf, Wi, Wc, Wo, bf_, bi_, bc_, bo_, Wint, w0b);
  lstm_zero<<<1064, 256, 0, stream>>>((uint4*)pub, (uint4*)flags, (float*)d_out, bout);
  lstm_main<<<256, 512, 0, stream>>>(Wint, w0b, x, Wout, (float*)d_out, pub, flags);
}

// Round 5
// 5849.826 us; speedup vs baseline: 4.0286x; 4.0286x over previous
//
#include <hip/hip_runtime.h>
#include <hip/hip_fp16.h>

// LSTM B=8192 S=1024 H=256 — round 5: round-4 dual-set stagger + STATIC wfrag
// indexing. Rounds 3/4 regressed because wfrag[mm][mi*4+ktl] (mi runtime)
// forced the register array to scratch (VGPR_Count=64, FETCH 70GB). Fix:
// wfrag[mm][0..3] = own-half K-tiles, [4..7] = peer-half; mi only in the
// LOAD ADDRESS. Everything else identical to round 4:
// 256 blocks x 512 thr, 1 block/CU; pairs {B, B^8} share 64 batch rows =
// 2 staggered sets of 32; per phase: spin (pre-satisfied) -> 8KB DMA ->
// acc-init + own-half K overlap DMA -> peer-half K -> gates -> publish.

typedef _Float16 f16x8 __attribute__((ext_vector_type(8)));
typedef float f32x4 __attribute__((ext_vector_type(4)));
typedef unsigned int u32;
typedef unsigned short u16;

#define WINT_OFF 0u
#define W0B_OFF  524288u
#define FLAG_OFF 528384u   // int[256 blocks][2 sets][16] = 32 KB
#define PUB_OFF  1048576u  // u16 quarters: (((s*2+pr)*128 + pid)*2 + mi)*4096 (8 MB)

static __device__ __forceinline__ float fast_exp2(float x) {
#if __has_builtin(__builtin_amdgcn_exp2f)
  return __builtin_amdgcn_exp2f(x);
#else
  return exp2f(x);
#endif
}
static __device__ __forceinline__ float fast_rcp(float x) {
#if __has_builtin(__builtin_amdgcn_rcpf)
  return __builtin_amdgcn_rcpf(x);
#else
  return 1.0f / x;
#endif
}
static __device__ __forceinline__ float fsig(float x) {
  return fast_rcp(1.0f + fast_exp2(-1.44269504f * x));
}
static __device__ __forceinline__ float ftanh_(float x) {
  float e = fast_exp2(2.88539008f * x);
  return 1.0f - 2.0f * fast_rcp(e + 1.0f);
}
static __device__ __forceinline__ u16 f16b(float f) {
  union { _Float16 h; u16 u; } cv; cv.h = (_Float16)f; return cv.u;
}
static __device__ __forceinline__ float h2f(u16 u) {
  union { u16 u; _Float16 h; } cv; cv.u = u; return (float)cv.h;
}

// Wint[n'][k], n' = j*4+g (gates of one j adjacent); w0b = packed fp16 {w0, bias}.
__global__ void lstm_prep(const float* __restrict__ Wf, const float* __restrict__ Wi,
                          const float* __restrict__ Wc, const float* __restrict__ Wo,
                          const float* __restrict__ bf_, const float* __restrict__ bi_,
                          const float* __restrict__ bc_, const float* __restrict__ bo_,
                          u16* __restrict__ Wint, u32* __restrict__ w0b) {
  int np = blockIdx.x;      // 0..1023
  int k  = threadIdx.x;     // 0..255
  int g = np & 3, j = np >> 2;
  const float* Ws = (g == 0) ? Wf : (g == 1) ? Wi : (g == 2) ? Wc : Wo;
  Wint[np * 256 + k] = f16b(Ws[j * 257 + 1 + k]);
  if (k == 0) {
    const float* bs = (g == 0) ? bf_ : (g == 1) ? bi_ : (g == 2) ? bc_ : bo_;
    w0b[np] = (u32)f16b(Ws[j * 257]) | ((u32)f16b(bs[j]) << 16);
  }
}

// Zero parity-0 publish quarters of both sets (h_0 = 0), flags, out = bout.
__global__ void lstm_zero(uint4* __restrict__ pub4, uint4* __restrict__ flags4,
                          float* __restrict__ out, const float* __restrict__ bout) {
  int idx = blockIdx.x * 256 + threadIdx.x;
  uint4 z = uint4{0, 0, 0, 0};
  if (idx < 131072) pub4[idx] = z;                        // set0 parity0 (2 MB)
  else if (idx < 262144) pub4[idx - 131072 + 262144] = z; // set1 parity0 (2 MB)
  else if (idx < 264192) flags4[idx - 262144] = z;        // flags (32 KB)
  else { int o = idx - 264192; if (o < 8192) out[o] = bout[0]; }
}

__global__ __launch_bounds__(512, 2) void lstm_main(
    const u16* __restrict__ Wint, const u32* __restrict__ w0b,
    const float* __restrict__ x, const float* __restrict__ Wout,
    float* __restrict__ out, u16* __restrict__ pub, int* __restrict__ flags) {

  __shared__ __align__(16) u16 stg[2][2][32 * 128];  // [set][0=own half,1=peer half]
  __shared__ u32 lw0b[512];

  const int tid  = threadIdx.x;
  const int wv   = tid >> 6;
  const int lane = tid & 63;
  const int l15  = lane & 15;
  const int quad = lane >> 4;
  const int B    = blockIdx.x;
  const int mi   = (B >> 3) & 1;
  const int peer = B ^ 8;
  const int pid  = (B & 7) | ((B >> 4) << 3);   // pair 0..127
  const int rows0 = pid * 64;                   // set0: +[0,32), set1: +[32,64)

  // ---- one-time: W A-fragments. REGISTER index static: [half*4+ktl];
  // mi (runtime) appears only in the load ADDRESS. half 0 = own K-range
  // k in [mi*128,+128), half 1 = peer K-range.
  f16x8 wfrag[4][8];
#pragma unroll
  for (int mm = 0; mm < 4; ++mm)
#pragma unroll
    for (int half = 0; half < 2; ++half)
#pragma unroll
      for (int ktl = 0; ktl < 4; ++ktl) {
        int kofs = (half == 0 ? mi : 1 - mi) * 128 + ktl * 32;   // runtime, addr only
        wfrag[mm][half * 4 + ktl] = *(const f16x8*)(Wint +
            (size_t)(mi * 512 + (wv * 4 + mm) * 16 + l15) * 256 + kofs + quad * 8);
      }
  lw0b[tid] = w0b[mi * 512 + tid];
  ((uint4*)&stg[0][0][0])[tid] = uint4{0, 0, 0, 0};   // h_0 own halves = 0
  ((uint4*)&stg[1][0][0])[tid] = uint4{0, 0, 0, 0};

  float cst[2][4][2];
#pragma unroll
  for (int s = 0; s < 2; ++s)
#pragma unroll
    for (int mm = 0; mm < 4; ++mm)
#pragma unroll
      for (int bt = 0; bt < 2; ++bt) cst[s][mm][bt] = 0.0f;

  const float* xp[2] = { x + (size_t)(rows0 + l15) * 1024,
                         x + (size_t)(rows0 + 32 + l15) * 1024 };
  int* const myflag[2] = { flags + B * 32,    flags + B * 32 + 16 };
  int* const pflag[2]  = { flags + peer * 32, flags + peer * 32 + 16 };

  __syncthreads();

#pragma unroll 1
  for (int t = 0; t < 1024; ++t) {
    const int pr = t & 1;
#pragma unroll
    for (int s = 0; s < 2; ++s) {
      // 1. peer's h_t for this set (pre-satisfied: published one phase ago)
      while (__hip_atomic_load(pflag[s], __ATOMIC_RELAXED, __HIP_MEMORY_SCOPE_AGENT) < t)
        __builtin_amdgcn_s_sleep(1);

      // 2. DMA peer half -> stg[s][1] (in flight under acc-init + own-K)
      const u16* ppub = pub + (size_t)((((s * 2 + pr) * 128 + pid) * 2 + (1 - mi)) * 4096);
      __builtin_amdgcn_global_load_lds(
          (const __attribute__((address_space(1))) u32*)(ppub + tid * 8),
          (__attribute__((address_space(3))) u32*)(&stg[s][1][wv * 512]), 16, 0, 0);

      // 3. acc init = x*w0 + bias
      float xv0 = xp[s][t], xv1 = xp[s][16 * 1024 + t];
      f32x4 acc[4][2];
#pragma unroll
      for (int mm = 0; mm < 4; ++mm) {
        uint4 pk = *(const uint4*)&lw0b[(wv * 4 + mm) * 16 + quad * 4];
        u32 pka[4] = {pk.x, pk.y, pk.z, pk.w};
#pragma unroll
        for (int r = 0; r < 4; ++r) {
          float w0f = h2f((u16)pka[r]), bsf = h2f((u16)(pka[r] >> 16));
          acc[mm][0][r] = xv0 * w0f + bsf;
          acc[mm][1][r] = xv1 * w0f + bsf;
        }
      }

      // 4. own-half K (reads stg[s][0]; overlaps DMA) — wfrag[..][0..3]
#pragma unroll
      for (int ktl = 0; ktl < 4; ++ktl) {
        f16x8 bb[2];
#pragma unroll
        for (int bt = 0; bt < 2; ++bt) {
          int b = bt * 16 + l15;
          int c = (ktl * 4 + quad) ^ (b & 7);
          bb[bt] = *(const f16x8*)&stg[s][0][b * 128 + c * 8];
        }
#pragma unroll
        for (int mm = 0; mm < 4; ++mm)
#pragma unroll
          for (int bt = 0; bt < 2; ++bt)
            acc[mm][bt] = __builtin_amdgcn_mfma_f32_16x16x32_f16(
                wfrag[mm][ktl], bb[bt], acc[mm][bt], 0, 0, 0);
      }
      __syncthreads();   // DMA drained; all waves done with stg[s][0] h_t

      // 5. peer-half K (reads stg[s][1]) — wfrag[..][4..7]
#pragma unroll
      for (int ktl = 0; ktl < 4; ++ktl) {
        f16x8 bb[2];
#pragma unroll
        for (int bt = 0; bt < 2; ++bt) {
          int b = bt * 16 + l15;
          int c = (ktl * 4 + quad) ^ (b & 7);
          bb[bt] = *(const f16x8*)&stg[s][1][b * 128 + c * 8];
        }
#pragma unroll
        for (int mm = 0; mm < 4; ++mm)
#pragma unroll
          for (int bt = 0; bt < 2; ++bt)
            acc[mm][bt] = __builtin_amdgcn_mfma_f32_16x16x32_f16(
                wfrag[mm][4 + ktl], bb[bt], acc[mm][bt], 0, 0, 0);
      }

      // 6. elementwise: f,i,cs,o in one f32x4; h_{t+1} -> stg[s][0] (swizzled)
#pragma unroll
      for (int mm = 0; mm < 4; ++mm) {
        int jl = (wv * 4 + mm) * 4 + quad;   // local j 0..127
#pragma unroll
        for (int bt = 0; bt < 2; ++bt) {
          int b = bt * 16 + l15;
          float fg = acc[mm][bt][0], ig = acc[mm][bt][1];
          float cg = acc[mm][bt][2], og = acc[mm][bt][3];
          float c_ = fsig(fg) * cst[s][mm][bt] + fsig(ig) * ftanh_(cg);
          cst[s][mm][bt] = c_;
          float hv = fsig(og) * ftanh_(c_);
          stg[s][0][b * 128 + ((jl >> 3) ^ (b & 7)) * 8 + (jl & 7)] = f16b(hv);
        }
      }
      __syncthreads();   // stg[s][0] h_{t+1} complete; stg[s][1] reads done

      // 7. publish own half (one coalesced uint4/thread = 8 KB)
      uint4 v = ((const uint4*)&stg[s][0][0])[tid];
      u16* mypub = pub + (size_t)((((s * 2 + (pr ^ 1)) * 128 + pid) * 2 + mi) * 4096);
      *(uint4*)(mypub + tid * 8) = v;
      __syncthreads();   // all threads' stores drained (vmcnt 0) before flag
      if (tid == 0)
        __hip_atomic_store(myflag[s], t + 1, __ATOMIC_RELAXED, __HIP_MEMORY_SCOPE_AGENT);
    }
  }

  // ---- out[b] += (own-half h_1024) . Wout  (out pre-set to bout) ----
#pragma unroll
  for (int s = 0; s < 2; ++s) {
    int row = tid >> 4, seg = tid & 15;
    f16x8 hv = *(const f16x8*)&stg[s][0][row * 128 + (seg ^ (row & 7)) * 8];
    float a = 0.0f;
#pragma unroll
    for (int e = 0; e < 8; ++e) a += (float)hv[e] * Wout[mi * 128 + seg * 8 + e];
#pragma unroll
    for (int mask = 1; mask < 16; mask <<= 1) a += __shfl_xor(a, mask, 16);
    if (seg == 0) atomicAdd(&out[rows0 + s * 32 + row], a);
  }
}

extern "C" void kernel_launch(void* const* d_in, const int* in_sizes, int n_in,
                              void* d_out, int out_size, void* d_ws, size_t ws_size,
                              hipStream_t stream) {
  const float* x    = (const float*)d_in[0];
  const float* Wf   = (const float*)d_in[1];
  const float* bf_  = (const float*)d_in[2];
  const float* Wi   = (const float*)d_in[3];
  const float* bi_  = (const float*)d_in[4];
  const float* Wc   = (const float*)d_in[5];
  const float* bc_  = (const float*)d_in[6];
  const float* Wo   = (const float*)d_in[7];
  const float* bo_  = (const float*)d_in[8];
  const float* Wout = (const float*)d_in[9];
  const float* bout = (const float*)d_in[10];

  u16* Wint  = (u16*)((char*)d_ws + WINT_OFF);
  u32* w0b   = (u32*)((char*)d_ws + W0B_OFF);
  int* flags = (int*)((char*)d_ws + FLAG_OFF);
  u16* pub   = (u16*)((char*)d_ws + PUB_OFF);

  lstm_prep<<<1024, 256, 0, stream>>>(Wf, Wi, Wc, Wo, bf_, bi_, bc_, bo_, Wint, w0b);
  lstm_zero<<<1064, 256, 0, stream>>>((uint4*)pub, (uint4*)flags, (float*)d_out, bout);
  lstm_main<<<256, 512, 0, stream>>>(Wint, w0b, x, Wout, (float*)d_out, pub, flags);
}

// Round 6
// 5777.090 us; speedup vs baseline: 4.0793x; 1.0126x over previous
//
#include <hip/hip_runtime.h>
#include <hip/hip_fp16.h>

// LSTM B=8192 S=1024 H=256 — round 6: quarter-slice W => 2 blocks/CU.
// r5 (1 block/CU) exposed ~2.2us/phase of serial latency (barriers, DMA/store
// drains) with nothing to overlap. Fix: 512 blocks x 512 thr, <=128 regs
// (launch_bounds(512,4)) -> 16 waves/CU. Quads {b0,b0+8,+16,+24} (same XCD
// both dispatch maps) share 64 rows = 2 staggered sets of 32. Each block owns
// a j-QUARTER (64 j = 256 gate rows x 256 K fp16 = 64 regs, loaded once,
// STATIC reg indices: slots 0-1 own quarter, 2-7 peers cyclic; mi only in
// addresses). LDS h stage is quarter-major [set][4][32*64] so the 3x4KB peer
// DMAs land contiguously. XOR chunk swizzle: 2-way max bank conflicts.
// f,i,cs,o of one (b,j) in one acc f32x4; c-state fp32 in VGPRs.

typedef _Float16 f16x8 __attribute__((ext_vector_type(8)));
typedef float f32x4 __attribute__((ext_vector_type(4)));
typedef unsigned int u32;
typedef unsigned short u16;

#define WINT_OFF 0u
#define W0B_OFF  524288u
#define FLAG_OFF 528384u   // int[512 blocks][2 sets][16] = 64 KB
#define PUB_OFF  1048576u  // u16: (((s*2+pr)*128 + q)*4 + mi)*2048  (8 MB)

static __device__ __forceinline__ float fast_exp2(float x) {
#if __has_builtin(__builtin_amdgcn_exp2f)
  return __builtin_amdgcn_exp2f(x);
#else
  return exp2f(x);
#endif
}
static __device__ __forceinline__ float fast_rcp(float x) {
#if __has_builtin(__builtin_amdgcn_rcpf)
  return __builtin_amdgcn_rcpf(x);
#else
  return 1.0f / x;
#endif
}
static __device__ __forceinline__ float fsig(float x) {
  return fast_rcp(1.0f + fast_exp2(-1.44269504f * x));
}
static __device__ __forceinline__ float ftanh_(float x) {
  float e = fast_exp2(2.88539008f * x);
  return 1.0f - 2.0f * fast_rcp(e + 1.0f);
}
static __device__ __forceinline__ u16 f16b(float f) {
  union { _Float16 h; u16 u; } cv; cv.h = (_Float16)f; return cv.u;
}
static __device__ __forceinline__ float h2f(u16 u) {
  union { u16 u; _Float16 h; } cv; cv.u = u; return (float)cv.h;
}

// Wint[n'][k], n' = j*4+g; w0b = packed fp16 {w0, bias}.
__global__ void lstm_prep(const float* __restrict__ Wf, const float* __restrict__ Wi,
                          const float* __restrict__ Wc, const float* __restrict__ Wo,
                          const float* __restrict__ bf_, const float* __restrict__ bi_,
                          const float* __restrict__ bc_, const float* __restrict__ bo_,
                          u16* __restrict__ Wint, u32* __restrict__ w0b) {
  int np = blockIdx.x;      // 0..1023
  int k  = threadIdx.x;     // 0..255
  int g = np & 3, j = np >> 2;
  const float* Ws = (g == 0) ? Wf : (g == 1) ? Wi : (g == 2) ? Wc : Wo;
  Wint[np * 256 + k] = f16b(Ws[j * 257 + 1 + k]);
  if (k == 0) {
    const float* bs = (g == 0) ? bf_ : (g == 1) ? bi_ : (g == 2) ? bc_ : bo_;
    w0b[np] = (u32)f16b(Ws[j * 257]) | ((u32)f16b(bs[j]) << 16);
  }
}

// Zero parity-0 pub (h_0 = 0) for both sets, flags, out = bout.
__global__ void lstm_zero(uint4* __restrict__ pub4, uint4* __restrict__ flags4,
                          float* __restrict__ out, const float* __restrict__ bout) {
  int idx = blockIdx.x * 256 + threadIdx.x;
  uint4 z = uint4{0, 0, 0, 0};
  if (idx < 131072) pub4[idx] = z;               // (s0,pr0) 2 MB
  else if (idx < 262144) pub4[idx + 131072] = z; // (s1,pr0) 2 MB at blk idx 2
  else if (idx < 266240) flags4[idx - 262144] = z;          // 64 KB flags
  else { int o = idx - 266240; if (o < 8192) out[o] = bout[0]; }
}

__global__ __launch_bounds__(512, 4) void lstm_main(
    const u16* __restrict__ Wint, const u32* __restrict__ w0b,
    const float* __restrict__ x, const float* __restrict__ Wout,
    float* __restrict__ out, u16* __restrict__ pub, int* __restrict__ flags) {

  __shared__ __align__(16) u16 stg[2][4][32 * 64];  // [set][quarter][row*64+j']
  __shared__ u32 lw0b[256];

  const int tid  = threadIdx.x;
  const int wv   = tid >> 6;
  const int lane = tid & 63;
  const int l15  = lane & 15;
  const int quad = lane >> 4;
  const int B    = blockIdx.x;
  const int mi   = (B >> 3) & 3;                 // member 0..3
  const int q    = (B & 7) | ((B >> 5) << 3);    // quad 0..127
  const int b0   = (q & 7) | ((q >> 3) << 5);    // member-0 block id
  const int rows0 = q * 64;

  // ---- one-time: W A-fragments, 64 regs. Reg index STATIC: slot 0-1 = own
  // quarter k-range, slots 2-7 = peer quarters cyclic. mi only in addresses.
  f16x8 wfrag[2][8];
#pragma unroll
  for (int mm = 0; mm < 2; ++mm)
#pragma unroll
    for (int d = 0; d < 4; ++d)
#pragma unroll
      for (int kl = 0; kl < 2; ++kl) {
        int qq = (mi + d) & 3;                   // runtime, address only
        wfrag[mm][d * 2 + kl] = *(const f16x8*)(Wint +
            (size_t)(mi * 256 + (wv * 2 + mm) * 16 + l15) * 256
            + qq * 64 + kl * 32 + quad * 8);
      }
  if (tid < 256) lw0b[tid] = w0b[mi * 256 + tid];
  // zero own quarter h_0 in both sets
  ((uint4*)&stg[0][0][0])[tid] = uint4{0, 0, 0, 0};  // covers all of set 0
  ((uint4*)&stg[1][0][0])[tid] = uint4{0, 0, 0, 0};  // and set 1 (8 KB each)

  float cst[2][2][2];
#pragma unroll
  for (int s = 0; s < 2; ++s)
#pragma unroll
    for (int mm = 0; mm < 2; ++mm)
#pragma unroll
      for (int bt = 0; bt < 2; ++bt) cst[s][mm][bt] = 0.0f;

  const float* xp[2] = { x + (size_t)(rows0 + l15) * 1024,
                         x + (size_t)(rows0 + 32 + l15) * 1024 };
  int* const myflag[2] = { flags + B * 32, flags + B * 32 + 16 };
  int* pf[2][3];
#pragma unroll
  for (int d = 0; d < 3; ++d) {
    int pb = b0 + (((mi + d + 1) & 3) << 3);
#pragma unroll
    for (int s = 0; s < 2; ++s) pf[s][d] = flags + pb * 32 + s * 16;
  }

  __syncthreads();

#pragma unroll 1
  for (int t = 0; t < 1024; ++t) {
    const int pr = t & 1;
#pragma unroll
    for (int s = 0; s < 2; ++s) {
      // 1. all 3 peers published h_t for this set (pre-satisfied via stagger)
#pragma unroll
      for (int d = 0; d < 3; ++d)
        while (__hip_atomic_load(pf[s][d], __ATOMIC_RELAXED, __HIP_MEMORY_SCOPE_AGENT) < t)
          __builtin_amdgcn_s_sleep(1);

      // 2. DMA 3 peer quarters (12 x 1KB wave-chunks over 8 waves)
      const u16* pubS = pub + (size_t)(((s * 2 + pr) * 128 + q) * 4) * 2048;
      u16* stgS = &stg[s][0][0];
#pragma unroll
      for (int rep = 0; rep < 2; ++rep) {
        int f = wv + rep * 8;
        if (f < 12) {
          int d = (f >> 2) + 1, c = f & 3;
          int qq = (mi + d) & 3;
          __builtin_amdgcn_global_load_lds(
              (const __attribute__((address_space(1))) u32*)
                  (pubS + (size_t)qq * 2048 + c * 512 + lane * 8),
              (__attribute__((address_space(3))) u32*)(stgS + qq * 2048 + c * 512),
              16, 0, 0);
        }
      }

      // 3. acc init = x*w0 + bias
      float xv0 = xp[s][t], xv1 = xp[s][16 * 1024 + t];
      f32x4 acc[2][2];
#pragma unroll
      for (int mm = 0; mm < 2; ++mm) {
        uint4 pk = *(const uint4*)&lw0b[(wv * 2 + mm) * 16 + quad * 4];
        u32 pka[4] = {pk.x, pk.y, pk.z, pk.w};
#pragma unroll
        for (int r = 0; r < 4; ++r) {
          float w0f = h2f((u16)pka[r]), bsf = h2f((u16)(pka[r] >> 16));
          acc[mm][0][r] = xv0 * w0f + bsf;
          acc[mm][1][r] = xv1 * w0f + bsf;
        }
      }

      // 4. own-quarter K (slots 0-1; reads own quarter; overlaps DMA)
#pragma unroll
      for (int kl = 0; kl < 2; ++kl) {
        f16x8 bb[2];
#pragma unroll
        for (int bt = 0; bt < 2; ++bt) {
          int b = bt * 16 + l15;
          int c = (kl * 4 + quad) ^ (b & 7);
          bb[bt] = *(const f16x8*)(stgS + mi * 2048 + b * 64 + c * 8);
        }
#pragma unroll
        for (int mm = 0; mm < 2; ++mm)
#pragma unroll
          for (int bt = 0; bt < 2; ++bt)
            acc[mm][bt] = __builtin_amdgcn_mfma_f32_16x16x32_f16(
                wfrag[mm][kl], bb[bt], acc[mm][bt], 0, 0, 0);
      }
      __syncthreads();   // DMA drained; own-quarter h_t reads done

      // 5. peer-quarter K (slots 2-7)
#pragma unroll
      for (int d = 1; d < 4; ++d)
#pragma unroll
        for (int kl = 0; kl < 2; ++kl) {
          int qq = (mi + d) & 3;   // address only
          f16x8 bb[2];
#pragma unroll
          for (int bt = 0; bt < 2; ++bt) {
            int b = bt * 16 + l15;
            int c = (kl * 4 + quad) ^ (b & 7);
            bb[bt] = *(const f16x8*)(stgS + qq * 2048 + b * 64 + c * 8);
          }
#pragma unroll
          for (int mm = 0; mm < 2; ++mm)
#pragma unroll
            for (int bt = 0; bt < 2; ++bt)
              acc[mm][bt] = __builtin_amdgcn_mfma_f32_16x16x32_f16(
                  wfrag[mm][d * 2 + kl], bb[bt], acc[mm][bt], 0, 0, 0);
        }

      // 6. elementwise; h_{t+1} -> own quarter (swizzled image)
#pragma unroll
      for (int mm = 0; mm < 2; ++mm) {
        int jl = (wv * 2 + mm) * 4 + quad;   // local j 0..63
#pragma unroll
        for (int bt = 0; bt < 2; ++bt) {
          int b = bt * 16 + l15;
          float fg = acc[mm][bt][0], ig = acc[mm][bt][1];
          float cg = acc[mm][bt][2], og = acc[mm][bt][3];
          float c_ = fsig(fg) * cst[s][mm][bt] + fsig(ig) * ftanh_(cg);
          cst[s][mm][bt] = c_;
          float hv = fsig(og) * ftanh_(c_);
          stgS[mi * 2048 + b * 64 + ((jl >> 3) ^ (b & 7)) * 8 + (jl & 7)] = f16b(hv);
        }
      }
      __syncthreads();   // own-quarter h_{t+1} image complete

      // 7. publish own quarter (4 KB, 256 threads x uint4, fully coalesced)
      u16* mypub = pub + (size_t)((((s * 2 + (pr ^ 1)) * 128 + q) * 4 + mi)) * 2048;
      if (tid < 256) {
        uint4 v = *(const uint4*)(stgS + mi * 2048 + tid * 8);
        *(uint4*)(mypub + tid * 8) = v;
      }
      __syncthreads();   // all publish stores drained (vmcnt 0) before flag
      if (tid == 0)
        __hip_atomic_store(myflag[s], t + 1, __ATOMIC_RELAXED, __HIP_MEMORY_SCOPE_AGENT);
    }
  }

  // ---- out[b] += (own-quarter h_1024) . Wout  (out pre-set to bout) ----
#pragma unroll
  for (int s = 0; s < 2; ++s) {
    if (tid < 256) {
      int row = tid >> 3, ch = tid & 7;
      f16x8 hv = *(const f16x8*)(&stg[s][0][0] + mi * 2048 + row * 64 + (ch ^ (row & 7)) * 8);
      float a = 0.0f;
#pragma unroll
      for (int e = 0; e < 8; ++e) a += (float)hv[e] * Wout[mi * 64 + ch * 8 + e];
#pragma unroll
      for (int mask = 1; mask < 8; mask <<= 1) a += __shfl_xor(a, mask, 8);
      if (ch == 0) atomicAdd(&out[rows0 + s * 32 + row], a);
    }
  }
}

extern "C" void kernel_launch(void* const* d_in, const int* in_sizes, int n_in,
                              void* d_out, int out_size, void* d_ws, size_t ws_size,
                              hipStream_t stream) {
  const float* x    = (const float*)d_in[0];
  const float* Wf   = (const float*)d_in[1];
  const float* bf_  = (const float*)d_in[2];
  const float* Wi   = (const float*)d_in[3];
  const float* bi_  = (const float*)d_in[4];
  const float* Wc   = (const float*)d_in[5];
  const float* bc_  = (const float*)d_in[6];
  const float* Wo   = (const float*)d_in[7];
  const float* bo_  = (const float*)d_in[8];
  const float* Wout = (const float*)d_in[9];
  const float* bout = (const float*)d_in[10];

  u16* Wint  = (u16*)((char*)d_ws + WINT_OFF);
  u32* w0b   = (u32*)((char*)d_ws + W0B_OFF);
  int* flags = (int*)((char*)d_ws + FLAG_OFF);
  u16* pub   = (u16*)((char*)d_ws + PUB_OFF);

  lstm_prep<<<1024, 256, 0, stream>>>(Wf, Wi, Wc, Wo, bf_, bi_, bc_, bo_, Wint, w0b);
  lstm_zero<<<1072, 256, 0, stream>>>((uint4*)pub, (uint4*)flags, (float*)d_out, bout);
  lstm_main<<<512, 512, 0, stream>>>(Wint, w0b, x, Wout, (float*)d_out, pub, flags);
}

// Round 7
// 4928.395 us; speedup vs baseline: 4.7817x; 1.1722x over previous
//
#include <hip/hip_runtime.h>
#include <hip/hip_fp16.h>

// LSTM B=8192 S=1024 H=256 — round 7: minimal-latency phase.
// r5/r6 proved wall = 2048 phases x phase_latency (lockstep recurrence); the
// phase was a serial chain of exposed latencies. This round cuts the chain:
//  - DMA for set s issued during set s^1's phase (lands a phase early)
//  - h published straight from registers (gate-tile layout: 4 consecutive j
//    per thread -> one 8B store); own half re-acquired via DMA like peer's
//  - x prefetched one step ahead into registers
//  - ONE barrier per phase (its implicit vmcnt(0) drains publish+DMA+x)
// 256 blocks x 512 thr, 1 block/CU (launch_bounds(512,2), ~240 regs).
// Pairs {B, B^8} share 64 rows = 2 staggered sets of 32. Each block owns
// j-half: wave wv owns j in [wv*16,+16); A-frags wfrag[gate][slot] with
// STATIC reg indices (slots 0-3 own k-half, 4-7 peer; mi only in addresses).

typedef _Float16 f16x8 __attribute__((ext_vector_type(8)));
typedef float f32x4 __attribute__((ext_vector_type(4)));
typedef unsigned int u32;
typedef unsigned short u16;

#define WINT_OFF 0u
#define W0B_OFF  524288u
#define FLAG_OFF 528384u   // int[256 blocks][2 sets][16] = 32 KB
#define PUB_OFF  1048576u  // u16[(set*2+par)*128+pair][2 half][4096] = 8 MB

static __device__ __forceinline__ float fast_exp2(float x) {
#if __has_builtin(__builtin_amdgcn_exp2f)
  return __builtin_amdgcn_exp2f(x);
#else
  return exp2f(x);
#endif
}
static __device__ __forceinline__ float fast_rcp(float x) {
#if __has_builtin(__builtin_amdgcn_rcpf)
  return __builtin_amdgcn_rcpf(x);
#else
  return 1.0f / x;
#endif
}
static __device__ __forceinline__ float fsig(float x) {
  return fast_rcp(1.0f + fast_exp2(-1.44269504f * x));
}
static __device__ __forceinline__ float ftanh_(float x) {
  float e = fast_exp2(2.88539008f * x);
  return 1.0f - 2.0f * fast_rcp(e + 1.0f);
}
static __device__ __forceinline__ u16 f16b(float f) {
  union { _Float16 h; u16 u; } cv; cv.h = (_Float16)f; return cv.u;
}
static __device__ __forceinline__ float h2f(u16 u) {
  union { u16 u; _Float16 h; } cv; cv.u = u; return (float)cv.h;
}
static __device__ __forceinline__ u16* pub_base(u16* pub, int set, int par,
                                                int pid, int half) {
  return pub + ((size_t)(((set * 2 + par) * 128 + pid) * 2 + half) << 12);
}

// Wint[n][k], n = g*256 + j (plain); w0b[n] = packed fp16 {w0, bias}.
__global__ void lstm_prep(const float* __restrict__ Wf, const float* __restrict__ Wi,
                          const float* __restrict__ Wc, const float* __restrict__ Wo,
                          const float* __restrict__ bf_, const float* __restrict__ bi_,
                          const float* __restrict__ bc_, const float* __restrict__ bo_,
                          u16* __restrict__ Wint, u32* __restrict__ w0b) {
  int n = blockIdx.x;       // 0..1023
  int k = threadIdx.x;      // 0..255
  int g = n >> 8, j = n & 255;
  const float* Ws = (g == 0) ? Wf : (g == 1) ? Wi : (g == 2) ? Wc : Wo;
  Wint[n * 256 + k] = f16b(Ws[j * 257 + 1 + k]);
  if (k == 0) {
    const float* bs = (g == 0) ? bf_ : (g == 1) ? bi_ : (g == 2) ? bc_ : bo_;
    w0b[n] = (u32)f16b(Ws[j * 257]) | ((u32)f16b(bs[j]) << 16);
  }
}

// Zero parity-0 pub of both sets (h_0 = 0), flags, out = bout.
__global__ void lstm_zero(uint4* __restrict__ pub4, uint4* __restrict__ flags4,
                          float* __restrict__ out, const float* __restrict__ bout) {
  int idx = blockIdx.x * 256 + threadIdx.x;
  uint4 z = uint4{0, 0, 0, 0};
  if (idx < 131072) pub4[idx] = z;                 // slot (s0,p0): 2 MB
  else if (idx < 262144) pub4[idx + 131072] = z;   // slot (s1,p0): 2 MB
  else if (idx < 264192) flags4[idx - 262144] = z; // 32 KB flags
  else { int o = idx - 264192; if (o < 8192) out[o] = bout[0]; }
}

__global__ __launch_bounds__(512, 2) void lstm_main(
    const u16* __restrict__ Wint, const u32* __restrict__ w0b,
    const float* __restrict__ x, const float* __restrict__ Wout,
    float* __restrict__ out, u16* __restrict__ pub, int* __restrict__ flags) {

  __shared__ __align__(16) u16 stg[2][2][4096];  // [set][0=own k-half,1=peer][32x128]

  const int tid  = threadIdx.x;
  const int wv   = tid >> 6;
  const int lane = tid & 63;
  const int l15  = lane & 15;
  const int quad = lane >> 4;
  const int B    = blockIdx.x;
  const int mi   = (B >> 3) & 1;
  const int peer = B ^ 8;
  const int pid  = (B & 7) | ((B >> 4) << 3);   // pair 0..127
  const int rows0 = pid * 64;

  // ---- one-time: W A-fragments (128 regs, STATIC indices) ----
  f16x8 wfrag[4][8];
#pragma unroll
  for (int g = 0; g < 4; ++g)
#pragma unroll
    for (int hm = 0; hm < 2; ++hm)
#pragma unroll
      for (int ktl = 0; ktl < 4; ++ktl) {
        int kbase = (hm == 0 ? mi : 1 - mi) * 128 + ktl * 32;  // runtime, addr only
        wfrag[g][hm * 4 + ktl] = *(const f16x8*)(Wint +
            (size_t)(g * 256 + mi * 128 + wv * 16 + l15) * 256 + kbase + quad * 8);
      }
  uint4 w0bv[4];
#pragma unroll
  for (int g = 0; g < 4; ++g)
    w0bv[g] = *(const uint4*)(w0b + g * 256 + mi * 128 + wv * 16 + quad * 4);

  // zero stg (h_0 images = 0): 32 KB = 2048 uint4
#pragma unroll
  for (int i = 0; i < 4; ++i) ((uint4*)stg)[tid + i * 512] = uint4{0, 0, 0, 0};

  float cst[2][2][4];   // [set][bt][r]: cell (b = bt*16+l15, j = wv*16+quad*4+r)
#pragma unroll
  for (int s = 0; s < 2; ++s)
#pragma unroll
    for (int bt = 0; bt < 2; ++bt)
#pragma unroll
      for (int r = 0; r < 4; ++r) cst[s][bt][r] = 0.0f;

  const float* xq = x + (size_t)rows0 * 1024;
  float xcur[2][2];
#pragma unroll
  for (int s = 0; s < 2; ++s)
#pragma unroll
    for (int bt = 0; bt < 2; ++bt)
      xcur[s][bt] = xq[(size_t)(s * 32 + bt * 16 + l15) * 1024];

  int* const myflag = flags + B * 32;
  int* const pfl    = flags + peer * 32;

  __syncthreads();

#pragma unroll 1
  for (int t = 0; t < 1024; ++t) {
#pragma unroll
    for (int s = 0; s < 2; ++s) {
      // 1. acc init = x*w0 + bias (no stg dependency)
      f32x4 acc[4][2];
#pragma unroll
      for (int g = 0; g < 4; ++g) {
        u32 pka[4] = {w0bv[g].x, w0bv[g].y, w0bv[g].z, w0bv[g].w};
#pragma unroll
        for (int r = 0; r < 4; ++r) {
          float w0f = h2f((u16)pka[r]), bsf = h2f((u16)(pka[r] >> 16));
          acc[g][0][r] = xcur[s][0] * w0f + bsf;
          acc[g][1][r] = xcur[s][1] * w0f + bsf;
        }
      }
      // x prefetch for (s, t+1) — drained by phase-end barrier
#pragma unroll
      for (int bt = 0; bt < 2; ++bt)
        xcur[s][bt] = xq[(size_t)(s * 32 + bt * 16 + l15) * 1024 + ((t + 1) & 1023)];

      // 2. K-loop: B-frags from stg[s] (DMA'd last phase), 8 MFMA per slot
#pragma unroll
      for (int hm = 0; hm < 2; ++hm)
#pragma unroll
        for (int ktl = 0; ktl < 4; ++ktl) {
          f16x8 bb[2];
#pragma unroll
          for (int bt = 0; bt < 2; ++bt) {
            int b = bt * 16 + l15;
            int cp = (ktl * 4 + quad) ^ (b & 15);
            bb[bt] = *(const f16x8*)(&stg[s][hm][0] + b * 128 + cp * 8);
          }
#pragma unroll
          for (int g = 0; g < 4; ++g)
#pragma unroll
            for (int bt = 0; bt < 2; ++bt)
              acc[g][bt] = __builtin_amdgcn_mfma_f32_16x16x32_f16(
                  wfrag[g][hm * 4 + ktl], bb[bt], acc[g][bt], 0, 0, 0);
        }

      // 3. poll + DMA for the OTHER set's next consumption (lands a phase early)
      const int tn = (s == 0) ? t : t + 1;   // step whose h we fetch for set s^1
      if (tn < 1024) {
        while (__hip_atomic_load(pfl + (s ^ 1) * 16, __ATOMIC_RELAXED,
                                 __HIP_MEMORY_SCOPE_AGENT) < tn)
          __builtin_amdgcn_s_sleep(1);
        const u16* srcO = pub_base(pub, s ^ 1, tn & 1, pid, mi);
        const u16* srcP = pub_base(pub, s ^ 1, tn & 1, pid, 1 - mi);
        __builtin_amdgcn_global_load_lds(
            (const __attribute__((address_space(1))) u32*)(srcO + wv * 512 + lane * 8),
            (__attribute__((address_space(3))) u32*)(&stg[s ^ 1][0][wv * 512]), 16, 0, 0);
        __builtin_amdgcn_global_load_lds(
            (const __attribute__((address_space(1))) u32*)(srcP + wv * 512 + lane * 8),
            (__attribute__((address_space(3))) u32*)(&stg[s ^ 1][1][wv * 512]), 16, 0, 0);
      }

      // 4. elementwise (f,i,cs,o across acc[g]) + publish straight from regs
      u16* pb = pub_base(pub, s, (t + 1) & 1, pid, mi);
#pragma unroll
      for (int bt = 0; bt < 2; ++bt) {
        int b = bt * 16 + l15;
        u32 lo, hi;
        {
          float h0, h1, h2, h3;
#pragma unroll
          for (int r = 0; r < 4; ++r) {
            float fg = acc[0][bt][r], ig = acc[1][bt][r];
            float cg = acc[2][bt][r], og = acc[3][bt][r];
            float c_ = fsig(fg) * cst[s][bt][r] + fsig(ig) * ftanh_(cg);
            cst[s][bt][r] = c_;
            float hv = fsig(og) * ftanh_(c_);
            if (r == 0) h0 = hv; else if (r == 1) h1 = hv;
            else if (r == 2) h2 = hv; else h3 = hv;
          }
          lo = (u32)f16b(h0) | ((u32)f16b(h1) << 16);
          hi = (u32)f16b(h2) | ((u32)f16b(h3) << 16);
        }
        int c16 = wv * 2 + (quad >> 1);
        int cp  = c16 ^ (b & 15);
        *(uint2*)(pb + b * 128 + cp * 8 + (quad & 1) * 4) = uint2{lo, hi};
      }

      // 5. single barrier: implicit vmcnt(0) drains publish + DMA + x loads
      __syncthreads();
      if (tid == 0)
        __hip_atomic_store(myflag + s * 16, t + 1, __ATOMIC_RELAXED,
                           __HIP_MEMORY_SCOPE_AGENT);
    }
  }

  // ---- out[b] += (own j-half of h_1024) . Wout  (out pre-set to bout) ----
  if (tid < 64) {
    int s = tid >> 5, b = tid & 31;
    const u16* pbase = pub_base(pub, s, 0, pid, mi);  // parity of t=1024 is 0
    float a = 0.0f;
#pragma unroll
    for (int c = 0; c < 16; ++c) {
      f16x8 hv = *(const f16x8*)(pbase + b * 128 + ((c ^ (b & 15)) * 8));
#pragma unroll
      for (int e = 0; e < 8; ++e) a += (float)hv[e] * Wout[mi * 128 + c * 8 + e];
    }
    atomicAdd(&out[rows0 + s * 32 + b], a);
  }
}

extern "C" void kernel_launch(void* const* d_in, const int* in_sizes, int n_in,
                              void* d_out, int out_size, void* d_ws, size_t ws_size,
                              hipStream_t stream) {
  const float* x    = (const float*)d_in[0];
  const float* Wf   = (const float*)d_in[1];
  const float* bf_  = (const float*)d_in[2];
  const float* Wi   = (const float*)d_in[3];
  const float* bi_  = (const float*)d_in[4];
  const float* Wc   = (const float*)d_in[5];
  const float* bc_  = (const float*)d_in[6];
  const float* Wo   = (const float*)d_in[7];
  const float* bo_  = (const float*)d_in[8];
  const float* Wout = (const float*)d_in[9];
  const float* bout = (const float*)d_in[10];

  u16* Wint  = (u16*)((char*)d_ws + WINT_OFF);
  u32* w0b   = (u32*)((char*)d_ws + W0B_OFF);
  int* flags = (int*)((char*)d_ws + FLAG_OFF);
  u16* pub   = (u16*)((char*)d_ws + PUB_OFF);

  lstm_prep<<<1024, 256, 0, stream>>>(Wf, Wi, Wc, Wo, bf_, bi_, bc_, bo_, Wint, w0b);
  lstm_zero<<<1064, 256, 0, stream>>>((uint4*)pub, (uint4*)flags, (float*)d_out, bout);
  lstm_main<<<256, 512, 0, stream>>>(Wint, w0b, x, Wout, (float*)d_out, pub, flags);
}